// Round 1
// 99.431 us; speedup vs baseline: 5.8969x; 5.8969x over previous
//
#include <hip/hip_runtime.h>
#include <math.h>

#define SEQ   4096
#define HD    64
#define NH    16
#define WHALF 256
#define QB    64     // queries per block = 4 waves x 16
#define KT    64     // key tile staged in LDS
#define KSTR  72     // row stride (bf16 elems) for K / V^T planes: 144B rows -> 16B-aligned, 2-way banks (free)
#define PSTR  40     // row stride (bf16 elems) for P planes: 80B rows -> 16B-aligned, 2-way banks

typedef __attribute__((ext_vector_type(8))) __bf16 bf16x8;
typedef __attribute__((ext_vector_type(8))) short short8v;
typedef __attribute__((ext_vector_type(4))) short short4v;
typedef __attribute__((ext_vector_type(4))) float f32x4;

// truncating f32 -> bf16 split: x ~= hi + lo, per-product error ~2^-16 relative
__device__ __forceinline__ short bftrunc(float x) {
    return (short)(__builtin_bit_cast(unsigned, x) >> 16);
}
__device__ __forceinline__ float bfhi_f(float x) {
    return __builtin_bit_cast(float, __builtin_bit_cast(unsigned, x) & 0xffff0000u);
}

#define MFMA16(A, B, C) __builtin_amdgcn_mfma_f32_16x16x32_bf16((A), (B), (C), 0, 0, 0)

__global__ __launch_bounds__(256, 3)
void swa_mfma_kernel(const float* __restrict__ q,
                     const float* __restrict__ k,
                     const float* __restrict__ v,
                     float* __restrict__ out) {
    __shared__ short Khi[KT * KSTR];     // [key][d]  bf16 hi
    __shared__ short Klo[KT * KSTR];     // [key][d]  bf16 lo
    __shared__ short VhiT[HD * KSTR];    // [d][key]  bf16 hi (transposed)
    __shared__ short VloT[HD * KSTR];    // [d][key]  bf16 lo (transposed)
    __shared__ short Phi[4][16 * PSTR];  // per-wave P^T->P buffer [q][key(32)] hi
    __shared__ short Plo[4][16 * PSTR];  // lo

    const int h    = blockIdx.y;
    const int q0   = blockIdx.x * QB;
    const int t    = threadIdx.x;
    const int lane = t & 63;
    const int w    = t >> 6;        // wave 0..3
    const int n15  = lane & 15;     // MFMA row/col index
    const int g    = lane >> 4;     // k-chunk group 0..3
    const int qrow = q0 + w * 16 + n15;   // this lane's query (D-col of swapped QK)

    // ---- Q fragments (B-operand of S^T = K·Q^T): lane needs Q[qrow][32c + 8g + j], pre-scaled, split ----
    bf16x8 qh[2], ql[2];
    {
        const float* qp = q + ((size_t)h * SEQ + qrow) * HD;
        #pragma unroll
        for (int c = 0; c < 2; ++c) {
            const float4* p4 = reinterpret_cast<const float4*>(qp + 32 * c + 8 * g);
            float4 a = p4[0], b = p4[1];
            float xs[8] = {a.x, a.y, a.z, a.w, b.x, b.y, b.z, b.w};
            short8v hi8, lo8;
            #pragma unroll
            for (int j = 0; j < 8; ++j) {
                float x = xs[j] * 0.125f;           // fold in 1/sqrt(64)
                hi8[j] = bftrunc(x);
                lo8[j] = bftrunc(x - bfhi_f(x));
            }
            qh[c] = __builtin_bit_cast(bf16x8, hi8);
            ql[c] = __builtin_bit_cast(bf16x8, lo8);
        }
    }

    // O^T accumulators: accO[dt][r] = O^T[d = dt*16 + 4g + r][q = n15]
    f32x4 accO[4];
    #pragma unroll
    for (int dt = 0; dt < 4; ++dt) accO[dt] = (f32x4){0.f, 0.f, 0.f, 0.f};
    float m = -1e30f, lsum = 0.f;

    int k0 = q0 - WHALF;           if (k0 < 0) k0 = 0;           // multiples of 64 -> all tiles full
    int k1 = q0 + QB - 1 + WHALF;  if (k1 > SEQ - 1) k1 = SEQ - 1;

    const float4* kb4 = reinterpret_cast<const float4*>(k + ((size_t)h * SEQ) * HD);
    const float4* vb4 = reinterpret_cast<const float4*>(v + ((size_t)h * SEQ) * HD);

    for (int kt = k0; kt <= k1; kt += KT) {
        __syncthreads();   // previous tile fully consumed
        // ---- stage: K row-major, V transposed; both split hi/lo ----
        #pragma unroll
        for (int i = 0; i < 4; ++i) {
            int flat = t + i * 256;          // float4 index in 64x64 tile
            int row  = flat >> 4;            // key row
            int c4   = flat & 15;            // float4 column
            float4 kv = kb4[(size_t)(kt + row) * (HD / 4) + c4];
            short4v h4, l4;
            #pragma unroll
            for (int j = 0; j < 4; ++j) {
                float x = ((const float*)&kv)[j];
                h4[j] = bftrunc(x);
                l4[j] = bftrunc(x - bfhi_f(x));
            }
            *reinterpret_cast<short4v*>(&Khi[row * KSTR + c4 * 4]) = h4;
            *reinterpret_cast<short4v*>(&Klo[row * KSTR + c4 * 4]) = l4;

            float4 vv = vb4[(size_t)(kt + row) * (HD / 4) + c4];
            #pragma unroll
            for (int j = 0; j < 4; ++j) {
                float x = ((const float*)&vv)[j];
                int d = c4 * 4 + j;
                VhiT[d * KSTR + row] = bftrunc(x);
                VloT[d * KSTR + row] = bftrunc(x - bfhi_f(x));
            }
        }
        __syncthreads();

        #pragma unroll
        for (int kc = 0; kc < 2; ++kc) {
            // ---- S^T = K·Q^T over two 16-key halves (A=K frag: row=key16+n15, k=32c+8g+j) ----
            f32x4 S[2];
            #pragma unroll
            for (int s = 0; s < 2; ++s) {
                const int key16 = kc * 32 + s * 16;
                const int krow  = (key16 + n15) * KSTR + 8 * g;
                bf16x8 kh0 = __builtin_bit_cast(bf16x8, *reinterpret_cast<const short8v*>(&Khi[krow]));
                bf16x8 kh1 = __builtin_bit_cast(bf16x8, *reinterpret_cast<const short8v*>(&Khi[krow + 32]));
                bf16x8 kl0 = __builtin_bit_cast(bf16x8, *reinterpret_cast<const short8v*>(&Klo[krow]));
                bf16x8 kl1 = __builtin_bit_cast(bf16x8, *reinterpret_cast<const short8v*>(&Klo[krow + 32]));
                f32x4 a0 = (f32x4){0.f, 0.f, 0.f, 0.f};
                f32x4 a1 = (f32x4){0.f, 0.f, 0.f, 0.f};
                a0 = MFMA16(kh0, qh[0], a0);  a1 = MFMA16(kh1, qh[1], a1);   // hi*hi
                a0 = MFMA16(kh0, ql[0], a0);  a1 = MFMA16(kh1, ql[1], a1);   // hi*lo
                a0 = MFMA16(kl0, qh[0], a0);  a1 = MFMA16(kl1, qh[1], a1);   // lo*hi
                S[s] = a0 + a1;
            }

            // ---- band mask + online softmax (lane-local: its query is n15) ----
            float sc[8];
            float tmax = -1e30f;
            #pragma unroll
            for (int s = 0; s < 2; ++s)
                #pragma unroll
                for (int r = 0; r < 4; ++r) {
                    int j = kt + kc * 32 + s * 16 + 4 * g + r;   // D row m = 4g+r -> key
                    bool valid = (j >= qrow - WHALF) && (j <= qrow + WHALF);
                    float x = valid ? S[s][r] : -1e30f;
                    sc[s * 4 + r] = x;
                    tmax = fmaxf(tmax, x);
                }
            tmax = fmaxf(tmax, __shfl_xor(tmax, 16));
            tmax = fmaxf(tmax, __shfl_xor(tmax, 32));
            const float mnew = fmaxf(m, tmax);
            const float corr = __expf(m - mnew);   // first tile: exp(-huge)=0
            lsum *= corr;
            #pragma unroll
            for (int dt = 0; dt < 4; ++dt) accO[dt] *= corr;
            m = mnew;

            float psum = 0.f;
            short4v ph[2], pl[2];
            #pragma unroll
            for (int s = 0; s < 2; ++s)
                #pragma unroll
                for (int r = 0; r < 4; ++r) {
                    float p = __expf(sc[s * 4 + r] - mnew);   // masked -> 0
                    psum += p;
                    ph[s][r] = bftrunc(p);
                    pl[s][r] = bftrunc(p - bfhi_f(p));
                }
            psum += __shfl_xor(psum, 16);
            psum += __shfl_xor(psum, 32);
            lsum += psum;

            // ---- P^T store (wave-local, no barrier): P[q=n15][key_in_chunk = s*16+4g+r] ----
            #pragma unroll
            for (int s = 0; s < 2; ++s) {
                int pb = n15 * PSTR + s * 16 + 4 * g;
                *reinterpret_cast<short4v*>(&Phi[w][pb]) = ph[s];
                *reinterpret_cast<short4v*>(&Plo[w][pb]) = pl[s];
            }

            // ---- PV: O^T += V^T · P^T  (A = V^T frag, B = P^T frag) ----
            {
                int pb = n15 * PSTR + 8 * g;
                bf16x8 pfh = __builtin_bit_cast(bf16x8, *reinterpret_cast<const short8v*>(&Phi[w][pb]));
                bf16x8 pfl = __builtin_bit_cast(bf16x8, *reinterpret_cast<const short8v*>(&Plo[w][pb]));
                #pragma unroll
                for (int dt = 0; dt < 4; ++dt) {
                    int vrow = (dt * 16 + n15) * KSTR + kc * 32 + 8 * g;
                    bf16x8 vh = __builtin_bit_cast(bf16x8, *reinterpret_cast<const short8v*>(&VhiT[vrow]));
                    bf16x8 vl = __builtin_bit_cast(bf16x8, *reinterpret_cast<const short8v*>(&VloT[vrow]));
                    accO[dt] = MFMA16(vh, pfh, accO[dt]);   // hi*hi
                    accO[dt] = MFMA16(vh, pfl, accO[dt]);   // hi*lo
                    accO[dt] = MFMA16(vl, pfh, accO[dt]);   // lo*hi
                }
            }
        }
    }

    // ---- epilogue: out[qrow][d] = accO/lsum, d = dt*16 + 4g + r ----
    const float inv = 1.0f / lsum;
    float* op = out + ((size_t)h * SEQ + qrow) * HD;
    #pragma unroll
    for (int dt = 0; dt < 4; ++dt) {
        *reinterpret_cast<f32x4*>(op + dt * 16 + 4 * g) = accO[dt] * inv;
    }
}

extern "C" void kernel_launch(void* const* d_in, const int* in_sizes, int n_in,
                              void* d_out, int out_size, void* d_ws, size_t ws_size,
                              hipStream_t stream) {
    const float* q = (const float*)d_in[0];
    const float* k = (const float*)d_in[1];
    const float* v = (const float*)d_in[2];
    float* out = (float*)d_out;

    dim3 grid(SEQ / QB, NH);   // 64 x 16 = 1024 blocks
    dim3 block(256);           // 4 waves
    hipLaunchKernelGGL(swa_mfma_kernel, grid, block, 0, stream, q, k, v, out);
}

// Round 2
// 52.210 us; speedup vs baseline: 11.2305x; 1.9045x over previous
//
#include <hip/hip_runtime.h>
#include <math.h>

#define SEQ   4096
#define HD    64
#define NH    16
#define WHALF 256
#define QB    128    // queries per block = 8 waves x 16
#define KT    64     // key tile staged in LDS
#define KSTR  72     // K plane row stride (d elems + pad): 144B rows
#define KSTRV 72     // V^T plane row stride (key elems + pad): 144B rows

typedef __attribute__((ext_vector_type(8))) __bf16 bf16x8;
typedef __attribute__((ext_vector_type(8))) short short8v;
typedef __attribute__((ext_vector_type(4))) short short4v;
typedef __attribute__((ext_vector_type(4))) __bf16 bf16x4;
typedef __attribute__((ext_vector_type(4))) float f32x4;

// truncating f32 -> bf16 split: x ~= hi + lo
__device__ __forceinline__ short bftrunc(float x) {
    return (short)(__builtin_bit_cast(unsigned, x) >> 16);
}
__device__ __forceinline__ float bfhi_f(float x) {
    return __builtin_bit_cast(float, __builtin_bit_cast(unsigned, x) & 0xffff0000u);
}

#define MFMA32(A, B, C) __builtin_amdgcn_mfma_f32_16x16x32_bf16((A), (B), (C), 0, 0, 0)

#if __has_builtin(__builtin_amdgcn_mfma_f32_16x16x16bf16_1k)
__device__ __forceinline__ f32x4 MFMA16(short4v a, short4v b, f32x4 c) {
    return __builtin_amdgcn_mfma_f32_16x16x16bf16_1k(a, b, c, 0, 0, 0);
}
#elif __has_builtin(__builtin_amdgcn_mfma_f32_16x16x16_bf16)
__device__ __forceinline__ f32x4 MFMA16(short4v a, short4v b, f32x4 c) {
    return __builtin_amdgcn_mfma_f32_16x16x16_bf16(__builtin_bit_cast(bf16x4, a),
                                                   __builtin_bit_cast(bf16x4, b), c, 0, 0, 0);
}
#else
__device__ __forceinline__ f32x4 MFMA16(short4v a, short4v b, f32x4 c) {
    f32x4 d;
    asm volatile("v_mfma_f32_16x16x16_bf16 %0, %1, %2, %3"
                 : "=v"(d) : "v"(a), "v"(b), "v"(c));
    return d;
}
#endif

__global__ __launch_bounds__(512, 4)
void swa_mfma2_kernel(const float* __restrict__ q,
                      const float* __restrict__ k,
                      const float* __restrict__ v,
                      float* __restrict__ out) {
    __shared__ short Khi[KT * KSTR];     // [key][d]  bf16 hi
    __shared__ short Klo[KT * KSTR];     // [key][d]  bf16 lo
    __shared__ short VhiT[HD * KSTRV];   // [d][key]  bf16 hi (transposed)
    __shared__ short VloT[HD * KSTRV];   // [d][key]  bf16 lo

    // ---- XCD-aware bijective swizzle: 512 blocks = 8 XCDs x 64; head-major chunks ----
    const int orig = blockIdx.x;
    const int work = ((orig & 7) << 6) + (orig >> 3);   // bijective (512 % 8 == 0)
    const int h    = work >> 5;          // 32 q-tiles per head -> 2 heads per XCD chunk
    const int q0   = (work & 31) * QB;

    const int t    = threadIdx.x;
    const int lane = t & 63;
    const int w    = t >> 6;             // wave 0..7
    const int n15  = lane & 15;
    const int g    = lane >> 4;          // 0..3
    const int qrow = q0 + w * 16 + n15;  // this lane's query

    // staging thread mapping for V (pre-transposed loads)
    const int dd  = t & 63;              // d index
    const int kr6 = t >> 6;              // 0..7

    // ---- Q fragments (B-operand of S^T = K·Q^T), pre-scaled, hi/lo split ----
    bf16x8 qh[2], ql[2];
    {
        const float* qp = q + ((size_t)h * SEQ + qrow) * HD;
        #pragma unroll
        for (int c = 0; c < 2; ++c) {
            const float4* p4 = reinterpret_cast<const float4*>(qp + 32 * c + 8 * g);
            float4 a = p4[0], b = p4[1];
            float xs[8] = {a.x, a.y, a.z, a.w, b.x, b.y, b.z, b.w};
            short8v hi8, lo8;
            #pragma unroll
            for (int j = 0; j < 8; ++j) {
                float x = xs[j] * 0.125f;
                hi8[j] = bftrunc(x);
                lo8[j] = bftrunc(x - bfhi_f(x));
            }
            qh[c] = __builtin_bit_cast(bf16x8, hi8);
            ql[c] = __builtin_bit_cast(bf16x8, lo8);
        }
    }

    f32x4 accO[4];
    #pragma unroll
    for (int dt = 0; dt < 4; ++dt) accO[dt] = (f32x4){0.f, 0.f, 0.f, 0.f};
    float m = -1e30f, lsum = 0.f;

    int k0 = q0 - WHALF;           if (k0 < 0) k0 = 0;
    int k1 = q0 + QB - 1 + WHALF;  if (k1 > SEQ - 1) k1 = SEQ - 1;
    // NOTE: (k1+1-k0) is always a multiple of 64 here -> no partial tiles.

    const int wlo = q0 + w * 16 - WHALF;        // wave's union window
    const int whi = q0 + w * 16 + 15 + WHALF;

    const float4* kb4 = reinterpret_cast<const float4*>(k + ((size_t)h * SEQ) * HD);
    const float*  vp  = v + ((size_t)h * SEQ) * HD;

    // ---- prefetch registers ----
    float4 kreg[2];
    float  vreg[8];

    // load tile kt into registers (K: 2x float4 coalesced; V: 8 scalars, transposed-friendly)
    #define LOADT(KTV)                                                          \
        {                                                                       \
            const int kt_ = (KTV);                                              \
            _Pragma("unroll")                                                   \
            for (int i = 0; i < 2; ++i)                                         \
                kreg[i] = kb4[(size_t)kt_ * 16 + (t + i * 512)];                \
            _Pragma("unroll")                                                   \
            for (int i = 0; i < 2; ++i)                                         \
                _Pragma("unroll")                                               \
                for (int j = 0; j < 4; ++j)                                     \
                    vreg[i * 4 + j] = vp[(size_t)(kt_ + i * 32 + 4 * kr6 + j) * HD + dd]; \
        }

    LOADT(k0);

    for (int kt = k0; kt <= k1; kt += KT) {
        __syncthreads();   // previous tile fully consumed

        // ---- store regs -> LDS with hi/lo split; all writes are conflict-free b64 ----
        #pragma unroll
        for (int i = 0; i < 2; ++i) {
            int flat = t + i * 512;
            int row  = flat >> 4;
            int c4   = flat & 15;
            float4 kv = kreg[i];
            short4v h4, l4;
            #pragma unroll
            for (int j = 0; j < 4; ++j) {
                float x = ((const float*)&kv)[j];
                h4[j] = bftrunc(x);
                l4[j] = bftrunc(x - bfhi_f(x));
            }
            *reinterpret_cast<short4v*>(&Khi[row * KSTR + c4 * 4]) = h4;
            *reinterpret_cast<short4v*>(&Klo[row * KSTR + c4 * 4]) = l4;
        }
        #pragma unroll
        for (int i = 0; i < 2; ++i) {
            short4v h4, l4;
            #pragma unroll
            for (int j = 0; j < 4; ++j) {
                float x = vreg[i * 4 + j];
                h4[j] = bftrunc(x);
                l4[j] = bftrunc(x - bfhi_f(x));
            }
            const int col = i * 32 + 4 * kr6;   // 4 consecutive keys at fixed d=dd
            *reinterpret_cast<short4v*>(&VhiT[dd * KSTRV + col]) = h4;
            *reinterpret_cast<short4v*>(&VloT[dd * KSTRV + col]) = l4;
        }
        __syncthreads();

        if (kt + KT <= k1) LOADT(kt + KT);   // issue next-tile loads; hide under compute

        #pragma unroll
        for (int kc = 0; kc < 2; ++kc) {
            const int cb = kt + kc * 32;
            if (cb > whi || cb + 31 < wlo) continue;   // wave-uniform chunk skip

            // ---- S^T = K·Q^T (16x16x32, 3-term split) ----
            f32x4 S[2];
            #pragma unroll
            for (int s = 0; s < 2; ++s) {
                const int krow = (kc * 32 + s * 16 + n15) * KSTR + 8 * g;
                bf16x8 kh0 = __builtin_bit_cast(bf16x8, *reinterpret_cast<const short8v*>(&Khi[krow]));
                bf16x8 kh1 = __builtin_bit_cast(bf16x8, *reinterpret_cast<const short8v*>(&Khi[krow + 32]));
                bf16x8 kl0 = __builtin_bit_cast(bf16x8, *reinterpret_cast<const short8v*>(&Klo[krow]));
                bf16x8 kl1 = __builtin_bit_cast(bf16x8, *reinterpret_cast<const short8v*>(&Klo[krow + 32]));
                f32x4 a0 = (f32x4){0.f, 0.f, 0.f, 0.f};
                f32x4 a1 = (f32x4){0.f, 0.f, 0.f, 0.f};
                a0 = MFMA32(kh0, qh[0], a0);  a1 = MFMA32(kh1, qh[1], a1);
                a0 = MFMA32(kh0, ql[0], a0);  a1 = MFMA32(kh1, ql[1], a1);
                a0 = MFMA32(kl0, qh[0], a0);  a1 = MFMA32(kl1, qh[1], a1);
                S[s] = a0 + a1;
            }

            // ---- band mask + online softmax (lane-local; its query is n15) ----
            float sc[8];
            float tmax = -1e30f;
            #pragma unroll
            for (int s = 0; s < 2; ++s)
                #pragma unroll
                for (int r = 0; r < 4; ++r) {
                    int j = cb + s * 16 + 4 * g + r;
                    bool valid = (j >= qrow - WHALF) && (j <= qrow + WHALF);
                    float x = valid ? S[s][r] : -1e30f;
                    sc[s * 4 + r] = x;
                    tmax = fmaxf(tmax, x);
                }
            tmax = fmaxf(tmax, __shfl_xor(tmax, 16));
            tmax = fmaxf(tmax, __shfl_xor(tmax, 32));
            const float mnew = fmaxf(m, tmax);
            const float corr = __expf(m - mnew);
            lsum *= corr;
            #pragma unroll
            for (int dt = 0; dt < 4; ++dt) accO[dt] *= corr;
            m = mnew;

            float psum = 0.f;
            short4v ph[2], pl[2];
            #pragma unroll
            for (int s = 0; s < 2; ++s)
                #pragma unroll
                for (int r = 0; r < 4; ++r) {
                    float p = __expf(sc[s * 4 + r] - mnew);
                    psum += p;
                    ph[s][r] = bftrunc(p);
                    pl[s][r] = bftrunc(p - bfhi_f(p));
                }
            psum += __shfl_xor(psum, 16);
            psum += __shfl_xor(psum, 32);
            lsum += psum;

            // ---- PV: O^T += V^T · P^T  via 16x16x16; B = P directly from registers ----
            #pragma unroll
            for (int s = 0; s < 2; ++s) {
                const int kl = kc * 32 + s * 16 + 4 * g;   // lane's key chunk (k = 4g+j)
                #pragma unroll
                for (int dt = 0; dt < 4; ++dt) {
                    const int vrow = (dt * 16 + n15) * KSTRV + kl;
                    short4v vh = *reinterpret_cast<const short4v*>(&VhiT[vrow]);
                    short4v vl = *reinterpret_cast<const short4v*>(&VloT[vrow]);
                    accO[dt] = MFMA16(vh, ph[s], accO[dt]);   // hi*hi
                    accO[dt] = MFMA16(vh, pl[s], accO[dt]);   // hi*lo
                    accO[dt] = MFMA16(vl, ph[s], accO[dt]);   // lo*hi
                }
            }
        }
    }

    // ---- epilogue: out[qrow][d], d = dt*16 + 4g + r ----
    const float inv = 1.0f / lsum;
    float* op = out + ((size_t)h * SEQ + qrow) * HD;
    #pragma unroll
    for (int dt = 0; dt < 4; ++dt) {
        *reinterpret_cast<f32x4*>(op + dt * 16 + 4 * g) = accO[dt] * inv;
    }
}

extern "C" void kernel_launch(void* const* d_in, const int* in_sizes, int n_in,
                              void* d_out, int out_size, void* d_ws, size_t ws_size,
                              hipStream_t stream) {
    const float* q = (const float*)d_in[0];
    const float* k = (const float*)d_in[1];
    const float* v = (const float*)d_in[2];
    float* out = (float*)d_out;

    dim3 grid(NH * (SEQ / QB));   // 512 blocks (1D for swizzle)
    dim3 block(512);              // 8 waves
    hipLaunchKernelGGL(swa_mfma2_kernel, grid, block, 0, stream, q, k, v, out);
}

// Round 3
// 49.279 us; speedup vs baseline: 11.8984x; 1.0595x over previous
//
#include <hip/hip_runtime.h>
#include <math.h>

#define SEQ   4096
#define HD    64
#define NH    16
#define WHALF 256
#define QB    128    // queries per block = 8 waves x 16
#define KT    64     // key tile staged in LDS
#define KSTR  72     // K plane stride (shorts): 144B rows -> b128 R/W at 8-phase floor
#define VSTR  136    // V interleaved stride (shorts): 272B rows -> b128 R/W at 8-phase floor

typedef __attribute__((ext_vector_type(8))) __bf16 bf16x8;
typedef __attribute__((ext_vector_type(8))) short short8v;
typedef __attribute__((ext_vector_type(4))) short short4v;
typedef __attribute__((ext_vector_type(4))) __bf16 bf16x4;
typedef __attribute__((ext_vector_type(4))) float f32x4;

// rounding f32 -> bf16 split: x ~= hi + lo, |lo| <= 0.5 ulp(hi)
__device__ __forceinline__ void bfsplit(float x, short& h, short& l) {
    __bf16 hb = (__bf16)x;
    float hf = (float)hb;
    __bf16 lb = (__bf16)(x - hf);
    h = __builtin_bit_cast(short, hb);
    l = __builtin_bit_cast(short, lb);
}

#define MFMA32(A, B, C) __builtin_amdgcn_mfma_f32_16x16x32_bf16((A), (B), (C), 0, 0, 0)

#if __has_builtin(__builtin_amdgcn_mfma_f32_16x16x16bf16_1k)
__device__ __forceinline__ f32x4 MFMA16(short4v a, short4v b, f32x4 c) {
    return __builtin_amdgcn_mfma_f32_16x16x16bf16_1k(a, b, c, 0, 0, 0);
}
#elif __has_builtin(__builtin_amdgcn_mfma_f32_16x16x16_bf16)
__device__ __forceinline__ f32x4 MFMA16(short4v a, short4v b, f32x4 c) {
    return __builtin_amdgcn_mfma_f32_16x16x16_bf16(__builtin_bit_cast(bf16x4, a),
                                                   __builtin_bit_cast(bf16x4, b), c, 0, 0, 0);
}
#else
__device__ __forceinline__ f32x4 MFMA16(short4v a, short4v b, f32x4 c) {
    f32x4 d;
    asm volatile("v_mfma_f32_16x16x16_bf16 %0, %1, %2, %3"
                 : "=v"(d) : "v"(a), "v"(b), "v"(c));
    return d;
}
#endif

#if __has_builtin(__builtin_amdgcn_exp2f)
#define EXP2F(x) __builtin_amdgcn_exp2f(x)
#else
#define EXP2F(x) __exp2f(x)
#endif

__global__ __launch_bounds__(512, 4)
void swa_mfma3_kernel(const float* __restrict__ q,
                      const float* __restrict__ k,
                      const float* __restrict__ v,
                      float* __restrict__ out) {
    __shared__ short Khi[KT * KSTR];    // [key][d] bf16 hi
    __shared__ short Klo[KT * KSTR];    // [key][d] bf16 lo
    __shared__ short VT[HD * VSTR];     // [d][key-group-of-4][hi4|lo4] interleaved

    // ---- XCD-aware bijective swizzle: 512 blocks = 8 XCDs x 64; head-major chunks ----
    const int orig = blockIdx.x;
    const int work = ((orig & 7) << 6) + (orig >> 3);
    const int h    = work >> 5;
    const int q0   = (work & 31) * QB;

    const int t    = threadIdx.x;
    const int lane = t & 63;
    const int w    = t >> 6;             // wave 0..7
    const int n15  = lane & 15;
    const int g    = lane >> 4;          // 0..3
    const int qrow = q0 + w * 16 + n15;  // this lane's query

    // scores computed in log2 domain: fold 1/sqrt(64) * log2(e) into Q
    const float SCALE = 0.125f * 1.44269504088896340736f;

    // ---- Q fragments (B-operand of S^T = K·Q^T), pre-scaled, hi/lo split ----
    bf16x8 qh[2], ql[2];
    {
        const float* qp = q + ((size_t)h * SEQ + qrow) * HD;
        #pragma unroll
        for (int c = 0; c < 2; ++c) {
            const float4* p4 = reinterpret_cast<const float4*>(qp + 32 * c + 8 * g);
            float4 a = p4[0], b = p4[1];
            float xs[8] = {a.x, a.y, a.z, a.w, b.x, b.y, b.z, b.w};
            short8v hi8, lo8;
            #pragma unroll
            for (int j = 0; j < 8; ++j) {
                short hh, ll;
                bfsplit(xs[j] * SCALE, hh, ll);
                hi8[j] = hh; lo8[j] = ll;
            }
            qh[c] = __builtin_bit_cast(bf16x8, hi8);
            ql[c] = __builtin_bit_cast(bf16x8, lo8);
        }
    }

    f32x4 accO[4];
    #pragma unroll
    for (int dt = 0; dt < 4; ++dt) accO[dt] = (f32x4){0.f, 0.f, 0.f, 0.f};
    float m = -1e30f, lsum = 0.f;   // lsum: per-lane partial, reduced in epilogue

    int k0 = q0 - WHALF;           if (k0 < 0) k0 = 0;
    int k1 = q0 + QB - 1 + WHALF;  if (k1 > SEQ - 1) k1 = SEQ - 1;
    // (k1+1-k0) is always a multiple of 64 -> no partial tiles, no row guards.

    const int wqmin = q0 + w * 16;
    const int wqmax = wqmin + 15;
    const int wlo   = wqmin - WHALF;   // wave union window
    const int whi   = wqmax + WHALF;

    const float4* kb4 = reinterpret_cast<const float4*>(k + ((size_t)h * SEQ) * HD);
    const float*  vp  = v + ((size_t)h * SEQ) * HD;

    // ---- prefetch registers ----
    // K: thread owns tile row (t>>3), 8 consecutive d at (t&7)*8  (contiguous 32B/lane)
    // V: thread owns d = lane, keys 8w..8w+7 (coalesced 256B per key-row)
    float4 kreg[2];
    float  vreg[8];

    #define LOADT(KTV)                                                       \
        {                                                                    \
            const int kt_ = (KTV);                                           \
            kreg[0] = kb4[(size_t)kt_ * 16 + t * 2 + 0];                     \
            kreg[1] = kb4[(size_t)kt_ * 16 + t * 2 + 1];                     \
            _Pragma("unroll")                                                \
            for (int j = 0; j < 8; ++j)                                      \
                vreg[j] = vp[(size_t)(kt_ + 8 * w + j) * HD + lane];         \
        }

    LOADT(k0);

    for (int kt = k0; kt <= k1; kt += KT) {
        __syncthreads();   // previous tile fully consumed

        // ---- stage regs -> LDS: hi/lo split, all writes b128 at the 8-phase bank floor ----
        {
            const float* kf = reinterpret_cast<const float*>(&kreg[0]);
            short8v h8, l8;
            #pragma unroll
            for (int j = 0; j < 8; ++j) {
                short hh, ll; bfsplit(kf[j], hh, ll);
                h8[j] = hh; l8[j] = ll;
            }
            *reinterpret_cast<short8v*>(&Khi[(t >> 3) * KSTR + (t & 7) * 8]) = h8;
            *reinterpret_cast<short8v*>(&Klo[(t >> 3) * KSTR + (t & 7) * 8]) = l8;

            #pragma unroll
            for (int half = 0; half < 2; ++half) {
                short8v m8;
                #pragma unroll
                for (int j = 0; j < 4; ++j) {
                    short hh, ll; bfsplit(vreg[half * 4 + j], hh, ll);
                    m8[j] = hh; m8[j + 4] = ll;
                }
                *reinterpret_cast<short8v*>(&VT[lane * VSTR + (2 * w + half) * 8]) = m8;
            }
        }
        __syncthreads();

        if (kt + KT <= k1) LOADT(kt + KT);   // issue next-tile loads; hide under compute

        #pragma unroll
        for (int kc = 0; kc < 2; ++kc) {
            const int cb = kt + kc * 32;
            if (cb > whi || cb + 31 < wlo) continue;   // wave-uniform chunk skip

            // ---- S^T = K·Q^T (16x16x32, 3-term split) ----
            f32x4 S[2];
            __builtin_amdgcn_s_setprio(1);
            #pragma unroll
            for (int s = 0; s < 2; ++s) {
                const int krow = (kc * 32 + s * 16 + n15) * KSTR + 8 * g;
                bf16x8 kh0 = __builtin_bit_cast(bf16x8, *reinterpret_cast<const short8v*>(&Khi[krow]));
                bf16x8 kh1 = __builtin_bit_cast(bf16x8, *reinterpret_cast<const short8v*>(&Khi[krow + 32]));
                bf16x8 kl0 = __builtin_bit_cast(bf16x8, *reinterpret_cast<const short8v*>(&Klo[krow]));
                bf16x8 kl1 = __builtin_bit_cast(bf16x8, *reinterpret_cast<const short8v*>(&Klo[krow + 32]));
                f32x4 a0 = (f32x4){0.f, 0.f, 0.f, 0.f};
                f32x4 a1 = (f32x4){0.f, 0.f, 0.f, 0.f};
                a0 = MFMA32(kh0, qh[0], a0);  a1 = MFMA32(kh1, qh[1], a1);
                a0 = MFMA32(kh0, ql[0], a0);  a1 = MFMA32(kh1, ql[1], a1);
                a0 = MFMA32(kl0, qh[0], a0);  a1 = MFMA32(kl1, qh[1], a1);
                S[s] = a0 + a1;
            }
            __builtin_amdgcn_s_setprio(0);

            // ---- band mask (boundary chunks only) + chunk max ----
            float sc[8];
            float tmax;
            const bool interior = (cb >= wqmax - WHALF) && (cb + 31 <= wqmin + WHALF);
            if (interior) {
                #pragma unroll
                for (int s = 0; s < 2; ++s)
                    #pragma unroll
                    for (int r = 0; r < 4; ++r) sc[s * 4 + r] = S[s][r];
                tmax = fmaxf(fmaxf(fmaxf(sc[0], sc[1]), fmaxf(sc[2], sc[3])),
                             fmaxf(fmaxf(sc[4], sc[5]), fmaxf(sc[6], sc[7])));
            } else {
                tmax = -1e30f;
                #pragma unroll
                for (int s = 0; s < 2; ++s)
                    #pragma unroll
                    for (int r = 0; r < 4; ++r) {
                        int j = cb + s * 16 + 4 * g + r;
                        bool valid = (j >= qrow - WHALF) && (j <= qrow + WHALF);
                        float x = valid ? S[s][r] : -1e30f;
                        sc[s * 4 + r] = x;
                        tmax = fmaxf(tmax, x);
                    }
            }
            tmax = fmaxf(tmax, __shfl_xor(tmax, 16));
            tmax = fmaxf(tmax, __shfl_xor(tmax, 32));   // all 4 g-lanes of a query agree

            // ---- defer-max: rescale only when some query's max actually grew (exact) ----
            if (__any(tmax > m)) {
                const float mnew = fmaxf(m, tmax);
                const float corr = EXP2F(m - mnew);   // first chunk: exp2(-huge) = 0
                lsum *= corr;
                #pragma unroll
                for (int dt = 0; dt < 4; ++dt) accO[dt] *= corr;
                m = mnew;
            }

            // ---- P = exp2(sc - m), per-lane lsum partial, hi/lo pack ----
            short4v ph[2], pl[2];
            #pragma unroll
            for (int s = 0; s < 2; ++s)
                #pragma unroll
                for (int r = 0; r < 4; ++r) {
                    float p = EXP2F(sc[s * 4 + r] - m);
                    lsum += p;
                    short hh, ll; bfsplit(p, hh, ll);
                    ph[s][r] = hh; pl[s][r] = ll;
                }

            // ---- PV: O^T += V^T · P^T via 16x16x16; one b128 read gives [vh|vl] ----
            __builtin_amdgcn_s_setprio(1);
            #pragma unroll
            for (int s = 0; s < 2; ++s) {
                const int grp = kc * 8 + s * 4 + g;   // 4-key group index
                #pragma unroll
                for (int dt = 0; dt < 4; ++dt) {
                    short8v vv = *reinterpret_cast<const short8v*>(&VT[(dt * 16 + n15) * VSTR + grp * 8]);
                    short4v vh = __builtin_shufflevector(vv, vv, 0, 1, 2, 3);
                    short4v vl = __builtin_shufflevector(vv, vv, 4, 5, 6, 7);
                    accO[dt] = MFMA16(vh, ph[s], accO[dt]);   // hi*hi
                    accO[dt] = MFMA16(vh, pl[s], accO[dt]);   // hi*lo
                    accO[dt] = MFMA16(vl, ph[s], accO[dt]);   // lo*hi
                }
            }
            __builtin_amdgcn_s_setprio(0);
        }
    }

    // ---- epilogue: reduce deferred lsum across g-lanes, normalize, store ----
    lsum += __shfl_xor(lsum, 16);
    lsum += __shfl_xor(lsum, 32);
    const float inv = 1.0f / lsum;
    float* op = out + ((size_t)h * SEQ + qrow) * HD;
    #pragma unroll
    for (int dt = 0; dt < 4; ++dt) {
        *reinterpret_cast<f32x4*>(op + dt * 16 + 4 * g) = accO[dt] * inv;
    }
}

extern "C" void kernel_launch(void* const* d_in, const int* in_sizes, int n_in,
                              void* d_out, int out_size, void* d_ws, size_t ws_size,
                              hipStream_t stream) {
    const float* q = (const float*)d_in[0];
    const float* k = (const float*)d_in[1];
    const float* v = (const float*)d_in[2];
    float* out = (float*)d_out;

    dim3 grid(NH * (SEQ / QB));   // 512 blocks (1D for swizzle)
    dim3 block(512);              // 8 waves
    hipLaunchKernelGGL(swa_mfma3_kernel, grid, block, 0, stream, q, k, v, out);
}